// Round 15
// baseline (540.091 us; speedup 1.0000x reference)
//
#include <hip/hip_runtime.h>
#include <float.h>

// VQ nearest-neighbor: 1-term bf16 MFMA (xh*eh) + best-4 margin certification +
// in-kernel exact-f32 candidate rescore + sliced full-scan fallback.
// dist = e2[k] - 2*dot.  Pass-1 error E<=0.5, key-quant 0.016; MARGIN=1.125:
//   v1-v0 >= M -> k0 exact.  v3-v0 < M -> full exact scan (rare, kernel 3).
//   else -> exact rescore of {k0..k3} in-block.
// R25 = K-SPLIT: each 64-row group handled by a PAIR of blocks (bid&1 = half
// of codebook, 2048 cols).  Grid 1024; LDS = 2x16KB = 32768 B exactly ->
// 4 blocks/CU (pool measured = 131072: R22 2x65536 packed, R16 2x67072
// didn't).  Per-CU LDS traffic UNCHANGED vs R22 (reads 32 waves x 0.5MB +
// writes 4 x 1MB = 20MB) but 32 waves/CU (was 16) + 4-way block independence
// hide the port/rendezvous latency.  R21-verified uniform 2-slot schedule
// (vmcnt(0)+lgkmcnt(0)+barrier), 64 single-chunk phases/block.
// Halves combine via device-scope ticket: both write per-row top-4 (post-
// decode) to resBuf[row][half]; threadfence; atomicAdd(ticket[pair]); second
// arriver merges (tie-at-rank-4 excluded by margin bound), certifies,
// rescores, fused code write (R24).  Tickets zeroed in vq_prep.
// Walls: VGPR 64-granule (R17); LDS pool 131072 (R16/R22); 1024-thr blocks
// don't co-schedule (R18/R23); epilogue VALU not binding (R20/R21).

#define HW 1024
#define CHW 262144
#define CODES_SIZE 8388608
#define NROWS 32768
#define KCB 4096
#define MARGIN 1.125f
#define DOFF 1024.0f

typedef short s16x8 __attribute__((ext_vector_type(8)));
typedef float f32x4 __attribute__((ext_vector_type(4)));

static __device__ __forceinline__ unsigned int bf16_rne(float f) {
    unsigned int u = __float_as_uint(f);
    return (u + 0x7FFFu + ((u >> 16) & 1u)) >> 16;
}
static __device__ __forceinline__ unsigned int f32_sortable(float d) {
    unsigned int s = __float_as_uint(d);
    return (s & 0x80000000u) ? ~s : (s | 0x80000000u);
}
static __device__ __forceinline__ void gload16(const uint4* g, uint4* lds) {
    __builtin_amdgcn_global_load_lds(
        (const __attribute__((address_space(1))) unsigned int*)g,
        (__attribute__((address_space(3))) unsigned int*)lds, 16, 0, 0);
}

// ---------- kernel 1: codebook -> eh bf16 plane + exact e2[k]; init ----------
__global__ __launch_bounds__(256) void vq_prep_e_e2(const float4* __restrict__ cb4,
                                                    uint4* __restrict__ eh4,
                                                    float* __restrict__ e2,
                                                    unsigned int* __restrict__ cntF,
                                                    unsigned int* __restrict__ ticket) {
    const int tid = threadIdx.x;
    const int gi = blockIdx.x * 256 + tid;           // 4096*32 granules
    if (gi == 0) *cntF = 0;
    if (tid == 0) ticket[blockIdx.x] = 0;            // 512 pair tickets
    const int k = gi >> 5, g = gi & 31;
    const float4 p = cb4[k * 64 + g * 2];
    const float4 q = cb4[k * 64 + g * 2 + 1];
    const float f[8] = {p.x, p.y, p.z, p.w, q.x, q.y, q.z, q.w};
    unsigned int h[8];
    float s = 0.0f;
    #pragma unroll
    for (int e = 0; e < 8; ++e) { h[e] = bf16_rne(f[e]); s = fmaf(f[e], f[e], s); }
    uint4 hi;
    hi.x = h[0] | (h[1] << 16); hi.y = h[2] | (h[3] << 16);
    hi.z = h[4] | (h[5] << 16); hi.w = h[6] | (h[7] << 16);
    eh4[gi] = hi;
    #pragma unroll
    for (int m = 1; m < 32; m <<= 1) s += __shfl_xor(s, m, 64);
    if ((tid & 31) == 0) e2[k] = s;
}

// ---------- kernel 2: K-split approx MFMA GEMM + combine + rescore + write ----------
// 512 thr / 8 waves: wr = wid>>1 (rows wr*16..+15), wc = wid&1 (cols wc*64..+63
// within this block's 2048-col half).  pair = bid>>1 (rows pair*64..+63),
// half = bid&1 (cols half*2048..+2047).  64 phases of 1 chunk (16 KB).
__global__ __launch_bounds__(512)
void vq_argmin_mfma(
        const float* __restrict__ x,
        const float* __restrict__ cb,
        const uint4* __restrict__ eh4,
        const float* __restrict__ e2g,
        float* __restrict__ out_idx,
        int* __restrict__ listF, unsigned int* __restrict__ cntF,
        unsigned long long* __restrict__ fbBest,
        float* __restrict__ out,
        uint4* __restrict__ resBuf,            // [32768 rows][2 halves][2 uint4]
        unsigned int* __restrict__ ticket) {   // [512 pairs]
    __shared__ uint4 EhS[2][1024];   // 2 slots x 16 KB = 32768 B exactly

    const int tid = threadIdx.x;
    const int lane = tid & 63, wid = tid >> 6;
    const int l15 = lane & 15, l4g = lane >> 4;
    const int wr = wid >> 1, wc = wid & 1;
    const int pair = blockIdx.x >> 1, hKf = blockIdx.x & 1;
    const int rowBase = pair * 64;
    const int colBase = hKf << 11;            // half-codebook base column
    const int roff = (blockIdx.x & 3) << 2;   // tile stagger (mod 16)

    // stage chunk `step` (of 64 in this half) into slot
    auto stage = [&](int slot, int step) {
        const int n = ((step >> 2) + roff) & 15, cc = step & 3;
        const int colbase = colBase + (n << 7);
        #pragma unroll
        for (int q = 0; q < 2; ++q) {
            const int idx0 = (wid * 2 + q) * 64;              // wave-uniform LDS slot
            const int col_loc = (idx0 >> 3) + (lane >> 3);
            const int g = lane & 7;
            const int srcg = g ^ (col_loc & 7);               // pre-swizzled source
            gload16(&eh4[(colbase + col_loc) * 32 + cc * 8 + srcg], &EhS[slot][idx0]);
        }
    };

    stage(0, 0);   // chunk 0 in flight; e2+X phase below hides its latency

    // ---- e2 prefetch for first tile (drained by X-phase data-dep waits) ----
    float e2p[4];
    #pragma unroll
    for (int j = 0; j < 4; ++j)
        e2p[j] = e2g[colBase + (roff << 7) + wc * 64 + j * 16 + l15] + DOFF;

    // ---- X phase: xh = bf16(-2x) -> regs (stride-HW dword loads) ----
    s16x8 xh_r[4][2];   // [cc][ks] = 32 VGPR
    {
        const int row_g = rowBase + wr * 16 + l15;
        const int b = row_g >> 10, hw = row_g & 1023;
        const float* xb = x + b * CHW + hw;
        #pragma unroll
        for (int cc = 0; cc < 4; ++cc)
            #pragma unroll
            for (int ks = 0; ks < 2; ++ks) {
                const int c0 = cc * 64 + (ks * 4 + l4g) * 8;
                unsigned int h[8];
                #pragma unroll
                for (int e = 0; e < 8; ++e) h[e] = bf16_rne(-2.0f * xb[(c0 + e) * HW]);
                union { s16x8 v; unsigned int u[4]; } th;
                th.u[0] = h[0] | (h[1] << 16); th.u[1] = h[2] | (h[3] << 16);
                th.u[2] = h[4] | (h[5] << 16); th.u[3] = h[6] | (h[7] << 16);
                xh_r[cc][ks] = th.v;
            }
    }

    // sorted best-4 per slot (4 slots = r), ascending f32 (packed keys are
    // positive normal floats -> f32 order == u32 order; min/med3 insert)
    float b4[4][4];
    #pragma unroll
    for (int s = 0; s < 4; ++s)
        #pragma unroll
        for (int t = 0; t < 4; ++t) b4[s][t] = FLT_MAX;

    for (int n = 0; n < 16; ++n) {              // 16 tiles per half
        const int tn = (n + roff) & 15;         // rotated tile index
        f32x4 acc[4];                            // C-init at cc0 from e2p

        #pragma unroll
        for (int cc = 0; cc < 4; ++cc) {
            const int step = n * 4 + cc;
            const int rs = cc & 1;               // slot = step&1 (4n even)
            // Uniform phase entry (R21/R22-proven): drain ALL vmem (stage
            // issued last phase + e2 prefetch), service this wave's ds_reads
            // of the slot about to be overwritten, rendezvous.
            asm volatile("s_waitcnt vmcnt(0)" ::: "memory");
            asm volatile("s_waitcnt lgkmcnt(0)" ::: "memory");
            asm volatile("s_barrier" ::: "memory");
            __builtin_amdgcn_sched_barrier(0);
            if (step + 1 < 64) stage(rs ^ 1, step + 1);
            if (cc == 0) {
                // C-init: acc = e2+DOFF (consumes e2p) ...
                #pragma unroll
                for (int j = 0; j < 4; ++j) {
                    f32x4 ci = {e2p[j], e2p[j], e2p[j], e2p[j]};
                    acc[j] = ci;
                }
                // ... then prefetch next tile's e2 (after stage in FIFO)
                if (n + 1 < 16) {
                    __builtin_amdgcn_sched_barrier(0);
                    const int tnn = (n + 1 + roff) & 15;
                    #pragma unroll
                    for (int j = 0; j < 4; ++j)
                        e2p[j] = e2g[colBase + (tnn << 7) + wc * 64 + j * 16 + l15] + DOFF;
                }
            }
            __builtin_amdgcn_s_setprio(1);
            #pragma unroll
            for (int ks = 0; ks < 2; ++ks) {
                const int cg = ks * 4 + l4g;
                #pragma unroll
                for (int j = 0; j < 4; ++j) {
                    const int col = wc * 64 + j * 16 + l15;
                    uint4 th = EhS[rs][col * 8 + (cg ^ (col & 7))];
                    s16x8 bh = *(s16x8*)&th;
                    acc[j] = __builtin_amdgcn_mfma_f32_16x16x32_bf16(
                        xh_r[cc][ks], bh, acc[j], 0, 0, 0);
                }
            }
            __builtin_amdgcn_s_setprio(0);
        }

        // epilogue: acc IS the offset distance; pack key + min/med3 insert.
        // 6-bit local key tn*4+j, quant <=0.016 << MARGIN.
        #pragma unroll
        for (int j = 0; j < 4; ++j) {
            const unsigned int kloc = (unsigned)(tn * 4 + j);
            #pragma unroll
            for (int r = 0; r < 4; ++r) {
                const float p = __uint_as_float(
                    (__float_as_uint(acc[j][r]) & ~63u) | kloc);
                const float o0 = b4[r][0], o1 = b4[r][1], o2 = b4[r][2];
                b4[r][0] = fminf(o0, p);
                b4[r][1] = __builtin_amdgcn_fmed3f(o0, b4[r][1], p);
                b4[r][2] = __builtin_amdgcn_fmed3f(o1, b4[r][2], p);
                b4[r][3] = __builtin_amdgcn_fmed3f(o2, b4[r][3], p);
            }
        }
    }

    // ---- decode 6-bit local keys to full k (half-global) ----
    float dv[4][4]; int dk[4][4];
    #pragma unroll
    for (int s = 0; s < 4; ++s)
        #pragma unroll
        for (int t = 0; t < 4; ++t) {
            const unsigned int u = __float_as_uint(b4[s][t]);
            const int kl = (int)(u & 63u);
            dv[s][t] = __uint_as_float(u & ~63u);
            dk[s][t] = colBase + ((kl >> 2) << 7) + wc * 64 + ((kl & 3) << 4) + l15;
        }

    // merge two sorted-4 (ascending f32) -> sorted top-4
    auto merge4 = [](float av[4], int ak[4],
                     const float bv[4], const int bk[4]) {
        float pv[4], qv[4]; int pk[4], qk[4];
        #pragma unroll
        for (int t = 0; t < 4; ++t) {
            const bool bl = bv[t] < av[t];
            pv[t] = bl ? bv[t] : av[t]; pk[t] = bl ? bk[t] : ak[t];
            qv[t] = bl ? av[t] : bv[t]; qk[t] = bl ? ak[t] : bk[t];
        }
        const bool c1 = qv[0] < pv[1];
        const float r1v = c1 ? qv[0] : pv[1]; const int r1k = c1 ? qk[0] : pk[1];
        const float x1v = c1 ? pv[1] : qv[0]; const int x1k = c1 ? pk[1] : qk[0];
        const bool c2 = pv[2] < x1v;
        const float r2v = c2 ? pv[2] : x1v;   const int r2k = c2 ? pk[2] : x1k;
        const bool c3 = qv[0] < pv[2];
        const float x2v = c3 ? pv[2] : qv[0]; const int x2k = c3 ? pk[2] : qk[0];
        const bool c4 = x2v < qv[1];
        const float t4v = c4 ? x2v : qv[1];   const int t4k = c4 ? x2k : qk[1];
        const bool c5 = pv[3] < t4v;
        const float r3v = c5 ? pv[3] : t4v;   const int r3k = c5 ? pk[3] : t4k;
        av[0] = pv[0]; ak[0] = pk[0];
        av[1] = r1v;   ak[1] = r1k;
        av[2] = r2v;   ak[2] = r2k;
        av[3] = r3v;   ak[3] = r3k;
    };

    // ---- cross-lane merge (16-lane k-groups share rows) ----
    #pragma unroll
    for (int m = 1; m < 16; m <<= 1) {
        #pragma unroll
        for (int s = 0; s < 4; ++s) {
            float bv[4]; int bk[4];
            #pragma unroll
            for (int t = 0; t < 4; ++t) {
                bv[t] = __shfl_xor(dv[s][t], m, 16);
                bk[t] = __shfl_xor(dk[s][t], m, 16);
            }
            merge4(dv[s], dk[s], bv, bk);
        }
    }

    // ---- cross-wave (wc) merge via LDS alias; then resBuf + ticket ----
    unsigned int* lbase = (unsigned int*)EhS;
    unsigned int* mbuf = lbase;                       // 64 rows x 8 u32
    int* flagRow = (int*)(lbase + 1024);              // 64
    int (*flagK)[4] = (int(*)[4])(lbase + 2048);      // 64 x 4
    unsigned int* pnflag = lbase + 4000;
    int* kRow = (int*)(lbase + 4096);                 // 64: final k or -1
    unsigned int* pOld = lbase + 4200;
    __syncthreads();    // ALL K-loop LDS reads complete before alias writes
    if (wc == 1 && l15 == 0) {
        #pragma unroll
        for (int r = 0; r < 4; ++r) {
            const int rl = wr * 16 + l4g * 4 + r;
            #pragma unroll
            for (int t = 0; t < 4; ++t) {
                mbuf[rl * 8 + t]     = __float_as_uint(dv[r][t]);
                mbuf[rl * 8 + 4 + t] = (unsigned int)dk[r][t];
            }
        }
    }
    __syncthreads();
    if (wc == 0 && l15 == 0) {
        #pragma unroll
        for (int r = 0; r < 4; ++r) {
            const int rl = wr * 16 + l4g * 4 + r;
            float bv[4]; int bk[4];
            #pragma unroll
            for (int t = 0; t < 4; ++t) {
                bv[t] = __uint_as_float(mbuf[rl * 8 + t]);
                bk[t] = (int)mbuf[rl * 8 + 4 + t];
            }
            merge4(dv[r], dk[r], bv, bk);          // own-half top-4 per row
            const int rg = rowBase + rl;
            uint4 v4, k4;
            v4.x = __float_as_uint(dv[r][0]); v4.y = __float_as_uint(dv[r][1]);
            v4.z = __float_as_uint(dv[r][2]); v4.w = __float_as_uint(dv[r][3]);
            k4.x = (unsigned)dk[r][0]; k4.y = (unsigned)dk[r][1];
            k4.z = (unsigned)dk[r][2]; k4.w = (unsigned)dk[r][3];
            resBuf[(rg * 2 + hKf) * 2 + 0] = v4;
            resBuf[(rg * 2 + hKf) * 2 + 1] = k4;
        }
    }
    __threadfence();            // release own-half results (device scope)
    __syncthreads();
    if (tid == 0) *pOld = atomicAdd(&ticket[pair], 1u);
    __syncthreads();
    if (*pOld == 0) return;     // first arriver: finisher handles the rest
    __threadfence();            // acquire other-half results

    // ---- finisher: merge halves, certify, flag, kRow ----
    if (tid == 0) *pnflag = 0;
    __syncthreads();
    if (wc == 0 && l15 == 0) {
        #pragma unroll
        for (int r = 0; r < 4; ++r) {
            const int rl = wr * 16 + l4g * 4 + r;
            const int rg = rowBase + rl;
            const uint4 v4 = resBuf[(rg * 2 + (hKf ^ 1)) * 2 + 0];
            const uint4 k4 = resBuf[(rg * 2 + (hKf ^ 1)) * 2 + 1];
            float bv[4]; int bk[4];
            bv[0] = __uint_as_float(v4.x); bv[1] = __uint_as_float(v4.y);
            bv[2] = __uint_as_float(v4.z); bv[3] = __uint_as_float(v4.w);
            bk[0] = (int)k4.x; bk[1] = (int)k4.y;
            bk[2] = (int)k4.z; bk[3] = (int)k4.w;
            merge4(dv[r], dk[r], bv, bk);          // full-codebook top-4
            const float v0 = dv[r][0];
            const float v1 = dv[r][1];
            const float v3 = dv[r][3];
            if (v3 - v0 < MARGIN) {                      // rare: full exact scan
                out_idx[rg] = -1.0f;                     // sentinel for gather_fb
                kRow[rl] = -1;
                fbBest[rg] = ~0ull;
                const unsigned int pos = atomicAdd(cntF, 1u);
                listF[pos] = rg;
            } else {
                out_idx[rg] = (float)dk[r][0];           // provisional/final
                kRow[rl] = dk[r][0];
                if (v1 - v0 < MARGIN) {                  // in-block exact rescore
                    const unsigned int pos = atomicAdd(pnflag, 1u);
                    flagRow[pos] = rl;
                    flagK[pos][0] = dk[r][0]; flagK[pos][1] = dk[r][1];
                    flagK[pos][2] = dk[r][2]; flagK[pos][3] = dk[r][3];
                }
            }
        }
    }
    __syncthreads();

    // ---- fused exact f32 rescore: wave per flagged row, x rows cache-warm ----
    const unsigned int nf = *pnflag;
    for (unsigned int e = wid; e < nf; e += 8) {
        const int rl = flagRow[e];
        const int rg = rowBase + rl;
        const int b = rg >> 10, hw = rg & 1023;
        const int kc = flagK[e][lane >> 4];
        const float* xb = x + b * CHW + hw;
        const float* eb = cb + kc * 256;
        float dot = 0.0f;
        #pragma unroll 4
        for (int t = lane & 15; t < 256; t += 16)
            dot = fmaf(xb[t * HW], eb[t], dot);
        #pragma unroll
        for (int m = 1; m < 16; m <<= 1) dot += __shfl_xor(dot, m, 16);
        const float d = fmaf(-2.0f, dot, e2g[kc]);
        float bd = d; int bk = kc;
        #pragma unroll
        for (int c = 1; c < 4; ++c) {
            const float od = __shfl(d, c * 16, 64);
            const int   ok = __shfl(kc, c * 16, 64);
            if (od < bd || (od == bd && ok < bk)) { bd = od; bk = ok; }
        }
        if (lane == 0) { out_idx[rg] = (float)bk; kRow[rl] = bk; }
    }
    __syncthreads();

    // ---- fused code write: 64 rows x 256 ch (64 KB, coalesced).
    // Sentinel rows (k<0, rare) written by vq_gather_fb after the fallback.
    {
        const int b0 = rowBase >> 10, hw0 = rowBase & 1023;
        const float4* cbb = (const float4*)cb;
        #pragma unroll
        for (int it = 0; it < 8; ++it) {
            const int item = it * 512 + tid;         // 64 rows x 64 c4-groups
            const int w6 = item & 63, c4 = item >> 6;
            const int k = kRow[w6];
            if (k >= 0) {
                const float4 v = cbb[k * 64 + c4];
                const int ob = b0 * CHW + (c4 * 4) * HW + hw0 + w6;
                out[ob] = v.x; out[ob + HW] = v.y;
                out[ob + 2 * HW] = v.z; out[ob + 3 * HW] = v.w;
            }
        }
    }
}

// ---------- kernel 3: sliced exact f32 full scan (8 blocks per flagged row) ----------
__global__ __launch_bounds__(256) void vq_fallback(
        const float* __restrict__ x, const float4* __restrict__ cb4,
        const float* __restrict__ e2g, const int* __restrict__ listF,
        const unsigned int* __restrict__ cntF,
        unsigned long long* __restrict__ fbBest) {
    __shared__ float xrow[256];
    const int li = blockIdx.x >> 3, sl = blockIdx.x & 7;
    if (li >= (int)*cntF) return;
    const int row = listF[li];
    const int b = row >> 10, hw = row & 1023;
    const int tid = threadIdx.x;
    xrow[tid] = x[b * CHW + tid * HW + hw];
    __syncthreads();
    float bestv = FLT_MAX; int bestk = 0;
    #pragma unroll
    for (int kk = 0; kk < 2; ++kk) {
        const int k = sl * 512 + kk * 256 + tid;
        float dot = 0.0f;
        #pragma unroll 8
        for (int c4 = 0; c4 < 64; ++c4) {
            const float4 e = cb4[k * 64 + c4];
            dot = fmaf(xrow[c4 * 4 + 0], e.x, dot);
            dot = fmaf(xrow[c4 * 4 + 1], e.y, dot);
            dot = fmaf(xrow[c4 * 4 + 2], e.z, dot);
            dot = fmaf(xrow[c4 * 4 + 3], e.w, dot);
        }
        const float d = fmaf(-2.0f, dot, e2g[k]);
        if (d < bestv) { bestv = d; bestk = k; }   // k ascending per thread
    }
    unsigned long long p = ((unsigned long long)f32_sortable(bestv) << 32)
                         | (unsigned int)bestk;    // tie -> smaller k wins
    #pragma unroll
    for (int m = 1; m < 64; m <<= 1) {
        const unsigned long long op = __shfl_xor(p, m, 64);
        p = op < p ? op : p;
    }
    if ((tid & 63) == 0) atomicMin(&fbBest[row], p);
}

// ---------- kernel 4 (slim): resolve fallback rows only, grid-stride ----------
__global__ __launch_bounds__(256) void vq_gather_fb(
        const float4* __restrict__ cb4, const int* __restrict__ listF,
        const unsigned int* __restrict__ cntF,
        const unsigned long long* __restrict__ fbBest,
        float* __restrict__ out_idx, float* __restrict__ out) {
    const unsigned int nf = *cntF;
    for (unsigned int item = blockIdx.x * 256 + threadIdx.x; item < nf * 64;
         item += gridDim.x * 256) {
        const int li = (int)(item >> 6), c4 = (int)(item & 63);
        const int row = listF[li];
        const int k = (int)(unsigned int)(fbBest[row] & 0xFFFFFFFFull);
        if (c4 == 0) out_idx[row] = (float)k;
        const int b = row >> 10, hw = row & 1023;
        const float4 v = cb4[k * 64 + c4];
        const int ob = b * CHW + (c4 * 4) * HW + hw;
        out[ob] = v.x; out[ob + HW] = v.y;
        out[ob + 2 * HW] = v.z; out[ob + 3 * HW] = v.w;
    }
}

extern "C" void kernel_launch(void* const* d_in, const int* in_sizes, int n_in,
                              void* d_out, int out_size, void* d_ws, size_t ws_size,
                              hipStream_t stream) {
    const float* x = (const float*)d_in[0];
    const float* cb = (const float*)d_in[1];
    float* out = (float*)d_out;
    float* out_idx = out + CODES_SIZE;

    char* wsb = (char*)d_ws;
    float* e2 = (float*)wsb;                                        // 16 KB
    unsigned int* cntF = (unsigned int*)(wsb + (16 << 10));         // 4 B
    int* listF = (int*)(wsb + (32 << 10));                          // 128 KB
    unsigned long long* fbBest = (unsigned long long*)(wsb + (256 << 10)); // 256 KB
    uint4* eh4 = (uint4*)(wsb + (512 << 10));                       // 2.10 MB
    unsigned int* ticket = (unsigned int*)(wsb + (2688 << 10));     // 2 KB
    uint4* resBuf = (uint4*)(wsb + (2816 << 10));                   // 2 MB

    vq_prep_e_e2<<<512, 256, 0, stream>>>((const float4*)cb, eh4, e2, cntF, ticket);
    vq_argmin_mfma<<<1024, 512, 0, stream>>>(x, cb, eh4, e2, out_idx,
                                             listF, cntF, fbBest, out,
                                             resBuf, ticket);
    vq_fallback<<<2048, 256, 0, stream>>>(x, (const float4*)cb, e2, listF, cntF, fbBest);
    vq_gather_fb<<<256, 256, 0, stream>>>((const float4*)cb, listF, cntF, fbBest,
                                          out_idx, out);
}

// Round 16
// 155.560 us; speedup vs baseline: 3.4719x; 3.4719x over previous
//
#include <hip/hip_runtime.h>
#include <float.h>

// VQ nearest-neighbor: 1-term bf16 MFMA (xh*eh) + best-4 margin certification +
// in-kernel exact-f32 candidate rescore + sliced full-scan fallback.
// dist = e2[k] - 2*dot.  Pass-1 error E<=0.5, key-quant 0.031; MARGIN=1.125:
//   v1-v0 >= M -> k0 exact.  v3-v0 < M -> full exact scan (rare, kernel 3).
//   else -> exact rescore of {k0..k3} in-block.
// R26 = R24 byte-for-byte (best verified: 155.2us total; argmin ~134.5us =
// pair-staged 4x16KB slots, 64 barriers, uniform vmcnt(0)+lgkmcnt(0)+barrier,
// dist-in-acc, stagger, setprio, fused code write + slim fallback gather).
// R25 post-mortem: K-split (grid 1024, 32KB blocks, ticket combine) collapsed
// to 5% MfmaUtil / 32% occupancy -- 4-block residency never materialized and
// 1-chunk lead starved against the 4-way-shared path.  Third confirmation:
// the ONLY working residency shape is 2 independent 8-wave 512-thr blocks/CU.
// Full wall map: VGPR 64-granule (R11/R17); 64KB/block LDS packing, pool =
// 131072 (R16/R22); 2-block independence mandatory (R18/R23/R25); barrier
// halving captured at pair granularity (R22); epilogue VALU null (R20/R21);
// K-split negative (R25); gather fusion captured (R24).  argmin sits at
// ~1.3x the ~103us LDS-port floor; remaining gap = mandatory rendezvous.

#define HW 1024
#define CHW 262144
#define CODES_SIZE 8388608
#define NROWS 32768
#define KCB 4096
#define MARGIN 1.125f
#define DOFF 1024.0f

typedef short s16x8 __attribute__((ext_vector_type(8)));
typedef float f32x4 __attribute__((ext_vector_type(4)));

static __device__ __forceinline__ unsigned int bf16_rne(float f) {
    unsigned int u = __float_as_uint(f);
    return (u + 0x7FFFu + ((u >> 16) & 1u)) >> 16;
}
static __device__ __forceinline__ unsigned int f32_sortable(float d) {
    unsigned int s = __float_as_uint(d);
    return (s & 0x80000000u) ? ~s : (s | 0x80000000u);
}
static __device__ __forceinline__ void gload16(const uint4* g, uint4* lds) {
    __builtin_amdgcn_global_load_lds(
        (const __attribute__((address_space(1))) unsigned int*)g,
        (__attribute__((address_space(3))) unsigned int*)lds, 16, 0, 0);
}

// ---------- kernel 1: codebook -> eh bf16 plane + exact e2[k]; cntF init ----------
__global__ __launch_bounds__(256) void vq_prep_e_e2(const float4* __restrict__ cb4,
                                                    uint4* __restrict__ eh4,
                                                    float* __restrict__ e2,
                                                    unsigned int* __restrict__ cntF) {
    const int tid = threadIdx.x;
    const int gi = blockIdx.x * 256 + tid;           // 4096*32 granules
    if (gi == 0) *cntF = 0;
    const int k = gi >> 5, g = gi & 31;
    const float4 p = cb4[k * 64 + g * 2];
    const float4 q = cb4[k * 64 + g * 2 + 1];
    const float f[8] = {p.x, p.y, p.z, p.w, q.x, q.y, q.z, q.w};
    unsigned int h[8];
    float s = 0.0f;
    #pragma unroll
    for (int e = 0; e < 8; ++e) { h[e] = bf16_rne(f[e]); s = fmaf(f[e], f[e], s); }
    uint4 hi;
    hi.x = h[0] | (h[1] << 16); hi.y = h[2] | (h[3] << 16);
    hi.z = h[4] | (h[5] << 16); hi.w = h[6] | (h[7] << 16);
    eh4[gi] = hi;
    #pragma unroll
    for (int m = 1; m < 32; m <<= 1) s += __shfl_xor(s, m, 64);
    if ((tid & 31) == 0) e2[k] = s;
}

// ---------- kernel 2: approx MFMA GEMM + med3 best-4 + rescore + code write ----------
// 512 thr / 8 waves: wr = wid>>1 (rows wr*16..+15), wc = wid&1 (cols wc*64..+63).
// Block: 64 rows x full K scan; 64 phases of 2 chunks (32 KB staged/phase),
// tile order rotated by 8*(bid&3) (stagger across co-resident blocks).
__global__ __launch_bounds__(512)
void vq_argmin_mfma(
        const float* __restrict__ x,
        const float* __restrict__ cb,
        const uint4* __restrict__ eh4,
        const float* __restrict__ e2g,
        float* __restrict__ out_idx,
        int* __restrict__ listF, unsigned int* __restrict__ cntF,
        unsigned long long* __restrict__ fbBest,
        float* __restrict__ out) {
    __shared__ uint4 EhS[4][1024];   // 2 halves x 2 chunks x 16 KB = 64 KB (all LDS)

    const int tid = threadIdx.x;
    const int lane = tid & 63, wid = tid >> 6;
    const int l15 = lane & 15, l4g = lane >> 4;
    const int wr = wid >> 1, wc = wid & 1;
    const int rowBase = blockIdx.x * 64;
    const int roff = (blockIdx.x & 3) << 3;   // stagger co-resident blocks

    // stage pair p (chunks 2p, 2p+1 = 32 KB) into half hf (slots hf*2, hf*2+1)
    auto stage = [&](int hf, int p) {
        #pragma unroll
        for (int q = 0; q < 4; ++q) {
            const int idx0 = (wid * 4 + q) * 64;      // 0..2047 spans 2 slots
            const int cip = idx0 >> 10;               // chunk-in-pair 0/1
            const int idxc = idx0 & 1023;             // index within slot
            const int chunk = 2 * p + cip;
            const int n = ((chunk >> 2) + roff) & 31, cc = chunk & 3;
            const int col_loc = (idxc >> 3) + (lane >> 3);
            const int g = lane & 7;
            const int srcg = g ^ (col_loc & 7);       // pre-swizzled source
            gload16(&eh4[(n * 128 + col_loc) * 32 + cc * 8 + srcg],
                    &EhS[hf * 2 + cip][idxc]);
        }
    };

    stage(0, 0);   // pair 0 in flight; e2+X phase below hides its latency

    // ---- e2 prefetch for first tile (drained by X-phase data-dep waits) ----
    float e2p[4];
    #pragma unroll
    for (int j = 0; j < 4; ++j)
        e2p[j] = e2g[(roff << 7) + wc * 64 + j * 16 + l15] + DOFF;

    // ---- X phase: xh = bf16(-2x) -> regs (stride-HW dword loads) ----
    s16x8 xh_r[4][2];   // [cc][ks] = 32 VGPR
    {
        const int row_g = rowBase + wr * 16 + l15;
        const int b = row_g >> 10, hw = row_g & 1023;
        const float* xb = x + b * CHW + hw;
        #pragma unroll
        for (int cc = 0; cc < 4; ++cc)
            #pragma unroll
            for (int ks = 0; ks < 2; ++ks) {
                const int c0 = cc * 64 + (ks * 4 + l4g) * 8;
                unsigned int h[8];
                #pragma unroll
                for (int e = 0; e < 8; ++e) h[e] = bf16_rne(-2.0f * xb[(c0 + e) * HW]);
                union { s16x8 v; unsigned int u[4]; } th;
                th.u[0] = h[0] | (h[1] << 16); th.u[1] = h[2] | (h[3] << 16);
                th.u[2] = h[4] | (h[5] << 16); th.u[3] = h[6] | (h[7] << 16);
                xh_r[cc][ks] = th.v;
            }
    }

    // sorted best-4 per slot (4 slots = r), ascending f32 (packed keys are
    // positive normal floats -> f32 order == u32 order; min/med3 insert = 4 ops)
    float b4[4][4];
    #pragma unroll
    for (int s = 0; s < 4; ++s)
        #pragma unroll
        for (int t = 0; t < 4; ++t) b4[s][t] = FLT_MAX;

    for (int n = 0; n < 32; ++n) {
        const int tn = (n + roff) & 31;         // rotated tile index
        f32x4 acc[4];                            // C-init at h0 from e2p

        #pragma unroll
        for (int h = 0; h < 2; ++h) {
            const int p = n * 2 + h;             // phase; pair p in half h (p&1==h)
            // Uniform phase entry (R21/R22-proven): drain ALL vmem (stage
            // issued last phase + e2 prefetch), service this wave's ds_reads
            // of the half about to be overwritten, rendezvous.
            asm volatile("s_waitcnt vmcnt(0)" ::: "memory");
            asm volatile("s_waitcnt lgkmcnt(0)" ::: "memory");
            asm volatile("s_barrier" ::: "memory");
            __builtin_amdgcn_sched_barrier(0);
            if (p + 1 < 64) stage(h ^ 1, p + 1);   // other half: readers passed barrier
            if (h == 0) {
                // C-init: acc = e2+DOFF (consumes e2p) ...
                #pragma unroll
                for (int j = 0; j < 4; ++j) {
                    f32x4 ci = {e2p[j], e2p[j], e2p[j], e2p[j]};
                    acc[j] = ci;
                }
                // ... then prefetch next tile's e2 (after stage in FIFO;
                // drained by next phase's vmcnt(0), consumed 2 phases later)
                if (n + 1 < 32) {
                    __builtin_amdgcn_sched_barrier(0);
                    const int tnn = (n + 1 + roff) & 31;
                    #pragma unroll
                    for (int j = 0; j < 4; ++j)
                        e2p[j] = e2g[(tnn << 7) + wc * 64 + j * 16 + l15] + DOFF;
                }
            }
            __builtin_amdgcn_s_setprio(1);
            #pragma unroll
            for (int cl = 0; cl < 2; ++cl) {       // 2 chunks this phase
                const int cc = 2 * h + cl;          // global c-chunk = xh index
                const int slot = h * 2 + cl;
                #pragma unroll
                for (int ks = 0; ks < 2; ++ks) {
                    const int cg = ks * 4 + l4g;
                    #pragma unroll
                    for (int j = 0; j < 4; ++j) {
                        const int col = wc * 64 + j * 16 + l15;
                        uint4 th = EhS[slot][col * 8 + (cg ^ (col & 7))];
                        s16x8 bh = *(s16x8*)&th;
                        acc[j] = __builtin_amdgcn_mfma_f32_16x16x32_bf16(
                            xh_r[cc][ks], bh, acc[j], 0, 0, 0);
                    }
                }
            }
            __builtin_amdgcn_s_setprio(0);
        }

        // epilogue: acc IS the offset distance; pack key + min/med3 insert
        // (~5 VALU/dist).  7-bit local key tn*4+j, quant <=0.031 << MARGIN.
        #pragma unroll
        for (int j = 0; j < 4; ++j) {
            const unsigned int kloc = (unsigned)(tn * 4 + j);
            #pragma unroll
            for (int r = 0; r < 4; ++r) {
                const float p = __uint_as_float(
                    (__float_as_uint(acc[j][r]) & ~127u) | kloc);
                const float o0 = b4[r][0], o1 = b4[r][1], o2 = b4[r][2];
                b4[r][0] = fminf(o0, p);
                b4[r][1] = __builtin_amdgcn_fmed3f(o0, b4[r][1], p);
                b4[r][2] = __builtin_amdgcn_fmed3f(o1, b4[r][2], p);
                b4[r][3] = __builtin_amdgcn_fmed3f(o2, b4[r][3], p);
            }
        }
    }

    // ---- decode 7-bit local keys to full k; (value, key) pairs from here ----
    float dv[4][4]; int dk[4][4];
    #pragma unroll
    for (int s = 0; s < 4; ++s)
        #pragma unroll
        for (int t = 0; t < 4; ++t) {
            const unsigned int u = __float_as_uint(b4[s][t]);
            const int kl = (int)(u & 127u);
            dv[s][t] = __uint_as_float(u & ~127u);
            dk[s][t] = ((kl >> 2) << 7) + wc * 64 + ((kl & 3) << 4) + l15;
        }

    // merge two sorted-4 (ascending f32) -> sorted top-4
    auto merge4 = [](float av[4], int ak[4],
                     const float bv[4], const int bk[4]) {
        float pv[4], qv[4]; int pk[4], qk[4];
        #pragma unroll
        for (int t = 0; t < 4; ++t) {
            const bool bl = bv[t] < av[t];
            pv[t] = bl ? bv[t] : av[t]; pk[t] = bl ? bk[t] : ak[t];
            qv[t] = bl ? av[t] : bv[t]; qk[t] = bl ? ak[t] : bk[t];
        }
        const bool c1 = qv[0] < pv[1];
        const float r1v = c1 ? qv[0] : pv[1]; const int r1k = c1 ? qk[0] : pk[1];
        const float x1v = c1 ? pv[1] : qv[0]; const int x1k = c1 ? pk[1] : qk[0];
        const bool c2 = pv[2] < x1v;
        const float r2v = c2 ? pv[2] : x1v;   const int r2k = c2 ? pk[2] : x1k;
        const bool c3 = qv[0] < pv[2];
        const float x2v = c3 ? pv[2] : qv[0]; const int x2k = c3 ? pk[2] : qk[0];
        const bool c4 = x2v < qv[1];
        const float t4v = c4 ? x2v : qv[1];   const int t4k = c4 ? x2k : qk[1];
        const bool c5 = pv[3] < t4v;
        const float r3v = c5 ? pv[3] : t4v;   const int r3k = c5 ? pk[3] : t4k;
        av[0] = pv[0]; ak[0] = pk[0];
        av[1] = r1v;   ak[1] = r1k;
        av[2] = r2v;   ak[2] = r2k;
        av[3] = r3v;   ak[3] = r3k;
    };

    // ---- cross-lane merge (16-lane k-groups share rows) ----
    #pragma unroll
    for (int m = 1; m < 16; m <<= 1) {
        #pragma unroll
        for (int s = 0; s < 4; ++s) {
            float bv[4]; int bk[4];
            #pragma unroll
            for (int t = 0; t < 4; ++t) {
                bv[t] = __shfl_xor(dv[s][t], m, 16);
                bk[t] = __shfl_xor(dk[s][t], m, 16);
            }
            merge4(dv[s], dk[s], bv, bk);
        }
    }

    // ---- cross-wave (wc) merge + flags + kRow, aliased into dead EhS ----
    unsigned int* lbase = (unsigned int*)EhS;
    unsigned int* mbuf = lbase;                       // 64 rows x 8 u32
    int* flagRow = (int*)(lbase + 1024);              // 64
    int (*flagK)[4] = (int(*)[4])(lbase + 2048);      // 64 x 4
    unsigned int* pnflag = lbase + 4000;
    int* kRow = (int*)(lbase + 4096);                 // 64: final k or -1
    __syncthreads();    // ALL K-loop LDS reads complete before alias writes
    if (tid == 0) *pnflag = 0;
    __syncthreads();
    if (wc == 1 && l15 == 0) {
        #pragma unroll
        for (int r = 0; r < 4; ++r) {
            const int rl = wr * 16 + l4g * 4 + r;
            #pragma unroll
            for (int t = 0; t < 4; ++t) {
                mbuf[rl * 8 + t]     = __float_as_uint(dv[r][t]);
                mbuf[rl * 8 + 4 + t] = (unsigned int)dk[r][t];
            }
        }
    }
    __syncthreads();
    if (wc == 0 && l15 == 0) {
        #pragma unroll
        for (int r = 0; r < 4; ++r) {
            const int rl = wr * 16 + l4g * 4 + r;
            float bv[4]; int bk[4];
            #pragma unroll
            for (int t = 0; t < 4; ++t) {
                bv[t] = __uint_as_float(mbuf[rl * 8 + t]);
                bk[t] = (int)mbuf[rl * 8 + 4 + t];
            }
            merge4(dv[r], dk[r], bv, bk);
            const int rg = rowBase + rl;
            const float v0 = dv[r][0];
            const float v1 = dv[r][1];
            const float v3 = dv[r][3];
            if (v3 - v0 < MARGIN) {                      // rare: full exact scan
                out_idx[rg] = -1.0f;                     // sentinel for gather_fb
                kRow[rl] = -1;
                fbBest[rg] = ~0ull;
                const unsigned int pos = atomicAdd(cntF, 1u);
                listF[pos] = rg;
            } else {
                out_idx[rg] = (float)dk[r][0];           // provisional/final
                kRow[rl] = dk[r][0];
                if (v1 - v0 < MARGIN) {                  // in-block exact rescore
                    const unsigned int pos = atomicAdd(pnflag, 1u);
                    flagRow[pos] = rl;
                    flagK[pos][0] = dk[r][0]; flagK[pos][1] = dk[r][1];
                    flagK[pos][2] = dk[r][2]; flagK[pos][3] = dk[r][3];
                }
            }
        }
    }
    __syncthreads();

    // ---- fused exact f32 rescore: wave per flagged row, x rows cache-warm ----
    const unsigned int nf = *pnflag;
    for (unsigned int e = wid; e < nf; e += 8) {
        const int rl = flagRow[e];
        const int rg = rowBase + rl;
        const int b = rg >> 10, hw = rg & 1023;
        const int kc = flagK[e][lane >> 4];
        const float* xb = x + b * CHW + hw;
        const float* eb = cb + kc * 256;
        float dot = 0.0f;
        #pragma unroll 4
        for (int t = lane & 15; t < 256; t += 16)
            dot = fmaf(xb[t * HW], eb[t], dot);
        #pragma unroll
        for (int m = 1; m < 16; m <<= 1) dot += __shfl_xor(dot, m, 16);
        const float d = fmaf(-2.0f, dot, e2g[kc]);
        float bd = d; int bk = kc;
        #pragma unroll
        for (int c = 1; c < 4; ++c) {
            const float od = __shfl(d, c * 16, 64);
            const int   ok = __shfl(kc, c * 16, 64);
            if (od < bd || (od == bd && ok < bk)) { bd = od; bk = ok; }
        }
        if (lane == 0) { out_idx[rg] = (float)bk; kRow[rl] = bk; }
    }
    __syncthreads();

    // ---- fused code write: 64 rows x 256 ch (64 KB, 256B-coalesced).
    // All 64 rows share b (64 | 1024); codebook is L2-warm.  Sentinel rows
    // (k<0, rare) are written by vq_gather_fb after the full-scan fallback.
    {
        const int b0 = rowBase >> 10, hw0 = rowBase & 1023;
        const float4* cbb = (const float4*)cb;
        #pragma unroll
        for (int it = 0; it < 8; ++it) {
            const int item = it * 512 + tid;         // 64 rows x 64 c4-groups
            const int w6 = item & 63, c4 = item >> 6;
            const int k = kRow[w6];
            if (k >= 0) {
                const float4 v = cbb[k * 64 + c4];
                const int ob = b0 * CHW + (c4 * 4) * HW + hw0 + w6;
                out[ob] = v.x; out[ob + HW] = v.y;
                out[ob + 2 * HW] = v.z; out[ob + 3 * HW] = v.w;
            }
        }
    }
}

// ---------- kernel 3: sliced exact f32 full scan (8 blocks per flagged row) ----------
__global__ __launch_bounds__(256) void vq_fallback(
        const float* __restrict__ x, const float4* __restrict__ cb4,
        const float* __restrict__ e2g, const int* __restrict__ listF,
        const unsigned int* __restrict__ cntF,
        unsigned long long* __restrict__ fbBest) {
    __shared__ float xrow[256];
    const int li = blockIdx.x >> 3, sl = blockIdx.x & 7;
    if (li >= (int)*cntF) return;
    const int row = listF[li];
    const int b = row >> 10, hw = row & 1023;
    const int tid = threadIdx.x;
    xrow[tid] = x[b * CHW + tid * HW + hw];
    __syncthreads();
    float bestv = FLT_MAX; int bestk = 0;
    #pragma unroll
    for (int kk = 0; kk < 2; ++kk) {
        const int k = sl * 512 + kk * 256 + tid;
        float dot = 0.0f;
        #pragma unroll 8
        for (int c4 = 0; c4 < 64; ++c4) {
            const float4 e = cb4[k * 64 + c4];
            dot = fmaf(xrow[c4 * 4 + 0], e.x, dot);
            dot = fmaf(xrow[c4 * 4 + 1], e.y, dot);
            dot = fmaf(xrow[c4 * 4 + 2], e.z, dot);
            dot = fmaf(xrow[c4 * 4 + 3], e.w, dot);
        }
        const float d = fmaf(-2.0f, dot, e2g[k]);
        if (d < bestv) { bestv = d; bestk = k; }   // k ascending per thread
    }
    unsigned long long p = ((unsigned long long)f32_sortable(bestv) << 32)
                         | (unsigned int)bestk;    // tie -> smaller k wins
    #pragma unroll
    for (int m = 1; m < 64; m <<= 1) {
        const unsigned long long op = __shfl_xor(p, m, 64);
        p = op < p ? op : p;
    }
    if ((tid & 63) == 0) atomicMin(&fbBest[row], p);
}

// ---------- kernel 4 (slim): resolve fallback rows only, grid-stride ----------
__global__ __launch_bounds__(256) void vq_gather_fb(
        const float4* __restrict__ cb4, const int* __restrict__ listF,
        const unsigned int* __restrict__ cntF,
        const unsigned long long* __restrict__ fbBest,
        float* __restrict__ out_idx, float* __restrict__ out) {
    const unsigned int nf = *cntF;
    for (unsigned int item = blockIdx.x * 256 + threadIdx.x; item < nf * 64;
         item += gridDim.x * 256) {
        const int li = (int)(item >> 6), c4 = (int)(item & 63);
        const int row = listF[li];
        const int k = (int)(unsigned int)(fbBest[row] & 0xFFFFFFFFull);
        if (c4 == 0) out_idx[row] = (float)k;
        const int b = row >> 10, hw = row & 1023;
        const float4 v = cb4[k * 64 + c4];
        const int ob = b * CHW + (c4 * 4) * HW + hw;
        out[ob] = v.x; out[ob + HW] = v.y;
        out[ob + 2 * HW] = v.z; out[ob + 3 * HW] = v.w;
    }
}

extern "C" void kernel_launch(void* const* d_in, const int* in_sizes, int n_in,
                              void* d_out, int out_size, void* d_ws, size_t ws_size,
                              hipStream_t stream) {
    const float* x = (const float*)d_in[0];
    const float* cb = (const float*)d_in[1];
    float* out = (float*)d_out;
    float* out_idx = out + CODES_SIZE;

    char* wsb = (char*)d_ws;
    float* e2 = (float*)wsb;                                        // 16 KB
    unsigned int* cntF = (unsigned int*)(wsb + (16 << 10));         // 4 B
    int* listF = (int*)(wsb + (32 << 10));                          // 128 KB
    unsigned long long* fbBest = (unsigned long long*)(wsb + (256 << 10)); // 256 KB
    uint4* eh4 = (uint4*)(wsb + (512 << 10));                       // 2.10 MB

    vq_prep_e_e2<<<512, 256, 0, stream>>>((const float4*)cb, eh4, e2, cntF);
    vq_argmin_mfma<<<512, 512, 0, stream>>>(x, cb, eh4, e2, out_idx,
                                            listF, cntF, fbBest, out);
    vq_fallback<<<2048, 256, 0, stream>>>(x, (const float4*)cb, e2, listF, cntF, fbBest);
    vq_gather_fb<<<256, 256, 0, stream>>>((const float4*)cb, listF, cntF, fbBest,
                                          out_idx, out);
}